// Round 1
// baseline (76.447 us; speedup 1.0000x reference)
//
#include <hip/hip_runtime.h>
#include <math.h>

#define NN 8192
#define NPHI 32
#define ROWS 4
#define TPB 256   // 4 waves of 64

// packed[j] = (y0, y1, y2, sq_j) with y = nodes[j] * W_theta[:,0]
__global__ void prep_kernel(const float* __restrict__ nodes,
                            const float* __restrict__ W_theta,
                            float4* __restrict__ packed) {
    int j = blockIdx.x * blockDim.x + threadIdx.x;
    if (j >= NN) return;
    float w0 = W_theta[0], w1 = W_theta[1], w2 = W_theta[2];
    float y0 = nodes[3 * j + 0] * w0;
    float y1 = nodes[3 * j + 1] * w1;
    float y2 = nodes[3 * j + 2] * w2;
    float sq = y0 * y0 + y1 * y1 + y2 * y2;
    packed[j] = make_float4(y0, y1, y2, sq);
}

__launch_bounds__(TPB, 8)
__global__ void maxdist_kernel(const float* __restrict__ prev,
                               const int* __restrict__ adj,
                               const float* __restrict__ W_phi,
                               const float4* __restrict__ packed,
                               float* __restrict__ out) {
    const int tid  = threadIdx.x;
    const int lane = tid & 63;
    const int wave = tid >> 6;            // 0..3 -> j-quarter
    const int i0   = blockIdx.x * ROWS;   // this block's 4 rows

    // Per-row constants: a = -2*y_i0 etc., s = sq_i
    float a[ROWS], b[ROWS], c[ROWS], s[ROWS], m[ROWS];
#pragma unroll
    for (int r = 0; r < ROWS; ++r) {
        float4 p = packed[i0 + r];
        a[r] = -2.0f * p.x;
        b[r] = -2.0f * p.y;
        c[r] = -2.0f * p.z;
        s[r] = p.w;
        m[r] = -INFINITY;
    }

    const int jbase = wave * (NN / 4) + lane;   // this wave's quarter
    const int iters = (NN / 4) / 64;            // 32

#pragma unroll 4
    for (int k = 0; k < iters; ++k) {
        const int j = jbase + k * 64;
        const float4 p  = packed[j];
        const float sqj = p.w;
#pragma unroll
        for (int r = 0; r < ROWS; ++r) {
            const int ad = adj[(size_t)(i0 + r) * NN + j];
            // d2 = sq_i + sq_j - 2*(y_i . y_j); a/b/c carry the -2 factor
            float dot = fmaf(a[r], p.x, fmaf(b[r], p.y, c[r] * p.z));
            float t   = s[r] + sqj + dot;
            m[r] = (ad > 0) ? fmaxf(m[r], t) : m[r];
        }
    }

    // wave-level max reduce (64 lanes)
#pragma unroll
    for (int r = 0; r < ROWS; ++r) {
        float v = m[r];
#pragma unroll
        for (int off = 32; off > 0; off >>= 1)
            v = fmaxf(v, __shfl_xor(v, off, 64));
        m[r] = v;
    }

    __shared__ float red[4][ROWS];
    if (lane == 0) {
#pragma unroll
        for (int r = 0; r < ROWS; ++r) red[wave][r] = m[r];
    }

    // mean of W_phi (wave-parallel, cheap, L2-resident)
    float wp = (lane < NPHI) ? W_phi[lane] : 0.0f;
#pragma unroll
    for (int off = 32; off > 0; off >>= 1) wp += __shfl_xor(wp, off, 64);
    const float wmean = wp / (float)NPHI;

    __syncthreads();

    if (tid < ROWS) {
        const int r = tid;
        float v = fmaxf(fmaxf(red[0][r], red[1][r]), fmaxf(red[2][r], red[3][r]));
        v = fmaxf(v, 0.0f);              // where() -inf guard + maximum(.,0)
        const float md = sqrtf(v);
        const int i = i0 + r;
        out[i] = (prev[i] + md * wmean) * 0.5f;
    }
}

extern "C" void kernel_launch(void* const* d_in, const int* in_sizes, int n_in,
                              void* d_out, int out_size, void* d_ws, size_t ws_size,
                              hipStream_t stream) {
    const float* prev    = (const float*)d_in[0];   // (N,)
    const float* nodes   = (const float*)d_in[1];   // (N,3)
    const int*   adj     = (const int*)d_in[2];     // (N,N)
    const float* W_phi   = (const float*)d_in[3];   // (32,)
    const float* W_theta = (const float*)d_in[4];   // (3,1)
    float* out = (float*)d_out;

    float4* packed = (float4*)d_ws;                 // 8192 * 16 B = 128 KB

    prep_kernel<<<(NN + TPB - 1) / TPB, TPB, 0, stream>>>(nodes, W_theta, packed);

    maxdist_kernel<<<NN / ROWS, TPB, 0, stream>>>(prev, adj, W_phi, packed, out);
}

// Round 3
// 64.736 us; speedup vs baseline: 1.1809x; 1.1809x over previous
//
#include <hip/hip_runtime.h>
#include <math.h>

#define NN 8192
#define NPHI 32
#define ROWS 4
#define TPB 256   // 4 waves of 64

typedef int  iv4 __attribute__((ext_vector_type(4)));   // clang vector: OK for nontemporal builtins

// packed[j] = (y0, y1, y2, sq_j) with y = nodes[j] * W_theta[:,0]
__global__ void prep_kernel(const float* __restrict__ nodes,
                            const float* __restrict__ W_theta,
                            float4* __restrict__ packed) {
    int j = blockIdx.x * blockDim.x + threadIdx.x;
    if (j >= NN) return;
    float w0 = W_theta[0], w1 = W_theta[1], w2 = W_theta[2];
    float y0 = nodes[3 * j + 0] * w0;
    float y1 = nodes[3 * j + 1] * w1;
    float y2 = nodes[3 * j + 2] * w2;
    float sq = y0 * y0 + y1 * y1 + y2 * y2;
    packed[j] = make_float4(y0, y1, y2, sq);
}

__launch_bounds__(TPB, 8)
__global__ void maxdist_kernel(const float* __restrict__ prev,
                               const int* __restrict__ adj,
                               const float* __restrict__ W_phi,
                               const float4* __restrict__ packed,
                               float* __restrict__ out) {
    const int tid  = threadIdx.x;
    const int lane = tid & 63;
    const int wave = tid >> 6;            // 0..3 -> j-quarter
    const int i0   = blockIdx.x * ROWS;   // this block's 4 rows

    // Per-row constants: a = -2*y_i, s = sq_i
    float a[ROWS], b[ROWS], c[ROWS], s[ROWS], m[ROWS];
#pragma unroll
    for (int r = 0; r < ROWS; ++r) {
        float4 p = packed[i0 + r];
        a[r] = -2.0f * p.x;
        b[r] = -2.0f * p.y;
        c[r] = -2.0f * p.z;
        s[r] = p.w;
        m[r] = -INFINITY;
    }

    // Each wave covers one contiguous quarter of columns; each lane owns 4
    // consecutive j's -> int4 adjacency loads (16 B/lane, 1 KB/wave-instr).
    const int qbase = wave * (NN / 4);          // quarter start
    const int iters = (NN / 4) / (64 * 4);      // 8

#pragma unroll 2
    for (int k = 0; k < iters; ++k) {
        const int j0 = qbase + k * 256 + lane * 4;   // first of this lane's 4 j's

        // packed for the 4 j's: 64 B contiguous per lane, L2-resident
        float4 p[4];
#pragma unroll
        for (int t = 0; t < 4; ++t) p[t] = packed[j0 + t];

#pragma unroll
        for (int r = 0; r < ROWS; ++r) {
            const iv4 av = __builtin_nontemporal_load(
                (const iv4*)(adj + (size_t)(i0 + r) * NN + j0));
#pragma unroll
            for (int t = 0; t < 4; ++t) {
                // d2 = sq_i + sq_j - 2*(y_i . y_j); a/b/c carry the -2
                float d2 = fmaf(a[r], p[t].x,
                            fmaf(b[r], p[t].y,
                             fmaf(c[r], p[t].z, s[r] + p[t].w)));
                d2 = (av[t] > 0) ? d2 : -INFINITY;
                m[r] = fmaxf(m[r], d2);
            }
        }
    }

    // wave-level max reduce (64 lanes)
#pragma unroll
    for (int r = 0; r < ROWS; ++r) {
        float v = m[r];
#pragma unroll
        for (int off = 32; off > 0; off >>= 1)
            v = fmaxf(v, __shfl_xor(v, off, 64));
        m[r] = v;
    }

    __shared__ float red[4][ROWS];
    if (lane == 0) {
#pragma unroll
        for (int r = 0; r < ROWS; ++r) red[wave][r] = m[r];
    }

    // mean of W_phi (wave-parallel, tiny)
    float wp = (lane < NPHI) ? W_phi[lane] : 0.0f;
#pragma unroll
    for (int off = 32; off > 0; off >>= 1) wp += __shfl_xor(wp, off, 64);
    const float wmean = wp / (float)NPHI;

    __syncthreads();

    if (tid < ROWS) {
        const int r = tid;
        float v = fmaxf(fmaxf(red[0][r], red[1][r]), fmaxf(red[2][r], red[3][r]));
        v = fmaxf(v, 0.0f);              // where() -inf guard + maximum(.,0)
        const float md = sqrtf(v);
        const int i = i0 + r;
        out[i] = (prev[i] + md * wmean) * 0.5f;
    }
}

extern "C" void kernel_launch(void* const* d_in, const int* in_sizes, int n_in,
                              void* d_out, int out_size, void* d_ws, size_t ws_size,
                              hipStream_t stream) {
    const float* prev    = (const float*)d_in[0];   // (N,)
    const float* nodes   = (const float*)d_in[1];   // (N,3)
    const int*   adj     = (const int*)d_in[2];     // (N,N)
    const float* W_phi   = (const float*)d_in[3];   // (32,)
    const float* W_theta = (const float*)d_in[4];   // (3,1)
    float* out = (float*)d_out;

    float4* packed = (float4*)d_ws;                 // 8192 * 16 B = 128 KB

    prep_kernel<<<(NN + TPB - 1) / TPB, TPB, 0, stream>>>(nodes, W_theta, packed);

    maxdist_kernel<<<NN / ROWS, TPB, 0, stream>>>(prev, adj, W_phi, packed, out);
}

// Round 4
// 58.729 us; speedup vs baseline: 1.3017x; 1.1023x over previous
//
#include <hip/hip_runtime.h>
#include <math.h>

#define NN 8192
#define NPHI 32
#define ROWS 4
#define TPB 256   // 4 waves of 64

typedef int iv4 __attribute__((ext_vector_type(4)));

// packed[j] = (y0, y1, y2, sq_j) with y = nodes[j] * W_theta[:,0]
__global__ void prep_kernel(const float* __restrict__ nodes,
                            const float* __restrict__ W_theta,
                            float4* __restrict__ packed) {
    int j = blockIdx.x * blockDim.x + threadIdx.x;
    if (j >= NN) return;
    float w0 = W_theta[0], w1 = W_theta[1], w2 = W_theta[2];
    float y0 = nodes[3 * j + 0] * w0;
    float y1 = nodes[3 * j + 1] * w1;
    float y2 = nodes[3 * j + 2] * w2;
    float sq = y0 * y0 + y1 * y1 + y2 * y2;
    packed[j] = make_float4(y0, y1, y2, sq);
}

// launch_bounds(256,4): VGPR cap 128 (not 64) -> room for 16 in-flight int4
// adjacency loads + packed regs. 4 blocks/CU resident = 16 waves/CU.
__launch_bounds__(TPB, 4)
__global__ void maxdist_kernel(const float* __restrict__ prev,
                               const int* __restrict__ adj,
                               const float* __restrict__ W_phi,
                               const float4* __restrict__ packed,
                               float* __restrict__ out) {
    const int tid  = threadIdx.x;
    const int lane = tid & 63;
    const int wave = tid >> 6;            // 0..3 -> j-quarter
    const int i0   = blockIdx.x * ROWS;   // this block's 4 rows

    float a[ROWS], b[ROWS], c[ROWS], s[ROWS], m[ROWS];
#pragma unroll
    for (int r = 0; r < ROWS; ++r) {
        float4 p = packed[i0 + r];
        a[r] = -2.0f * p.x;
        b[r] = -2.0f * p.y;
        c[r] = -2.0f * p.z;
        s[r] = p.w;
        m[r] = -INFINITY;
    }

    const int qbase = wave * (NN / 4);          // this wave's quarter
    const int iters = (NN / 4) / (64 * 4);      // 8

#pragma unroll 4
    for (int k = 0; k < iters; ++k) {
        const int j0 = qbase + k * 256 + lane * 4;

        // Issue all 4 adjacency loads first (plain loads: allow L2/L3
        // allocation -- adjacency ~= L3 size, replay hits are possible).
        iv4 av[ROWS];
#pragma unroll
        for (int r = 0; r < ROWS; ++r)
            av[r] = *(const iv4*)(adj + (size_t)(i0 + r) * NN + j0);

        float4 p[4];
#pragma unroll
        for (int t = 0; t < 4; ++t) p[t] = packed[j0 + t];

#pragma unroll
        for (int r = 0; r < ROWS; ++r) {
#pragma unroll
            for (int t = 0; t < 4; ++t) {
                float d2 = fmaf(a[r], p[t].x,
                            fmaf(b[r], p[t].y,
                             fmaf(c[r], p[t].z, s[r] + p[t].w)));
                d2 = (av[r][t] > 0) ? d2 : -INFINITY;
                m[r] = fmaxf(m[r], d2);
            }
        }
    }

    // wave-level max reduce
#pragma unroll
    for (int r = 0; r < ROWS; ++r) {
        float v = m[r];
#pragma unroll
        for (int off = 32; off > 0; off >>= 1)
            v = fmaxf(v, __shfl_xor(v, off, 64));
        m[r] = v;
    }

    __shared__ float red[4][ROWS];
    if (lane == 0) {
#pragma unroll
        for (int r = 0; r < ROWS; ++r) red[wave][r] = m[r];
    }

    float wp = (lane < NPHI) ? W_phi[lane] : 0.0f;
#pragma unroll
    for (int off = 32; off > 0; off >>= 1) wp += __shfl_xor(wp, off, 64);
    const float wmean = wp / (float)NPHI;

    __syncthreads();

    if (tid < ROWS) {
        const int r = tid;
        float v = fmaxf(fmaxf(red[0][r], red[1][r]), fmaxf(red[2][r], red[3][r]));
        v = fmaxf(v, 0.0f);
        const float md = sqrtf(v);
        const int i = i0 + r;
        out[i] = (prev[i] + md * wmean) * 0.5f;
    }
}

extern "C" void kernel_launch(void* const* d_in, const int* in_sizes, int n_in,
                              void* d_out, int out_size, void* d_ws, size_t ws_size,
                              hipStream_t stream) {
    const float* prev    = (const float*)d_in[0];
    const float* nodes   = (const float*)d_in[1];
    const int*   adj     = (const int*)d_in[2];
    const float* W_phi   = (const float*)d_in[3];
    const float* W_theta = (const float*)d_in[4];
    float* out = (float*)d_out;

    float4* packed = (float4*)d_ws;   // 128 KB

    prep_kernel<<<(NN + TPB - 1) / TPB, TPB, 0, stream>>>(nodes, W_theta, packed);

    maxdist_kernel<<<NN / ROWS, TPB, 0, stream>>>(prev, adj, W_phi, packed, out);
}

// Round 5
// 58.085 us; speedup vs baseline: 1.3161x; 1.0111x over previous
//
#include <hip/hip_runtime.h>
#include <math.h>

#define NN 8192
#define NPHI 32
#define ROWS 8
#define TPB 256   // 4 waves of 64

typedef int iv4 __attribute__((ext_vector_type(4)));

// packed[j] = (y0, y1, y2, sq_j) with y = nodes[j] * W_theta[:,0]
__global__ void prep_kernel(const float* __restrict__ nodes,
                            const float* __restrict__ W_theta,
                            float4* __restrict__ packed) {
    int j = blockIdx.x * blockDim.x + threadIdx.x;
    if (j >= NN) return;
    float w0 = W_theta[0], w1 = W_theta[1], w2 = W_theta[2];
    float y0 = nodes[3 * j + 0] * w0;
    float y1 = nodes[3 * j + 1] * w1;
    float y2 = nodes[3 * j + 2] * w2;
    float sq = y0 * y0 + y1 * y1 + y2 * y2;
    packed[j] = make_float4(y0, y1, y2, sq);
}

// ROWS=8: each packed float4 amortized over 8 adjacency loads -> VMEM issues
// per adjacency byte drop 25% vs ROWS=4; packed L2 traffic halves.
// lb(256,4): VGPR cap 128; live set ~98 regs -> headroom, no spills.
__launch_bounds__(TPB, 4)
__global__ void maxdist_kernel(const float* __restrict__ prev,
                               const int* __restrict__ adj,
                               const float* __restrict__ W_phi,
                               const float4* __restrict__ packed,
                               float* __restrict__ out) {
    const int tid  = threadIdx.x;
    const int lane = tid & 63;
    const int wave = tid >> 6;            // 0..3 -> j-quarter
    const int i0   = blockIdx.x * ROWS;

    float a[ROWS], b[ROWS], c[ROWS], s[ROWS], m[ROWS];
#pragma unroll
    for (int r = 0; r < ROWS; ++r) {
        float4 p = packed[i0 + r];
        a[r] = -2.0f * p.x;
        b[r] = -2.0f * p.y;
        c[r] = -2.0f * p.z;
        s[r] = p.w;
        m[r] = -INFINITY;   // running max of (sq_j - 2*dot); add s[r] at the end
    }

    const int qbase = wave * (NN / 4);
    const int iters = (NN / 4) / (64 * 4);      // 8

    for (int k = 0; k < iters; ++k) {
        const int j0 = qbase + k * 256 + lane * 4;

        // all 8 adjacency loads first: HBM misses start early
        iv4 av[ROWS];
#pragma unroll
        for (int r = 0; r < ROWS; ++r)
            av[r] = *(const iv4*)(adj + (size_t)(i0 + r) * NN + j0);

        float4 p[4];
#pragma unroll
        for (int t = 0; t < 4; ++t) p[t] = packed[j0 + t];

#pragma unroll
        for (int r = 0; r < ROWS; ++r) {
#pragma unroll
            for (int t = 0; t < 4; ++t) {
                // partial = sq_j - 2*(y_i . y_j); s_i added after the loop
                float d2 = fmaf(a[r], p[t].x,
                            fmaf(b[r], p[t].y,
                             fmaf(c[r], p[t].z, p[t].w)));
                d2 = (av[r][t] > 0) ? d2 : -INFINITY;
                m[r] = fmaxf(m[r], d2);
            }
        }
    }

    // wave-level max reduce
#pragma unroll
    for (int r = 0; r < ROWS; ++r) {
        float v = m[r];
#pragma unroll
        for (int off = 32; off > 0; off >>= 1)
            v = fmaxf(v, __shfl_xor(v, off, 64));
        m[r] = v;
    }

    __shared__ float red[4][ROWS];
    if (lane == 0) {
#pragma unroll
        for (int r = 0; r < ROWS; ++r) red[wave][r] = m[r];
    }

    float wp = (lane < NPHI) ? W_phi[lane] : 0.0f;
#pragma unroll
    for (int off = 32; off > 0; off >>= 1) wp += __shfl_xor(wp, off, 64);
    const float wmean = wp / (float)NPHI;

    __syncthreads();

    if (tid < ROWS) {
        const int r = tid;
        float v = fmaxf(fmaxf(red[0][r], red[1][r]), fmaxf(red[2][r], red[3][r]));
        v = s[0] * 0.0f + v;             // (keep s reg class trivial; no-op)
        float d2max = red[0][r];         // recompute properly below
        // combine: v = max over waves of (sq_j - 2 dot); full d2 = s_i + v
        d2max = fmaxf(fmaxf(red[0][r], red[1][r]), fmaxf(red[2][r], red[3][r]));
        const int i = i0 + r;
        const float si = packed[i].w;    // s_i (L2-hit)
        float d2 = si + d2max;           // -inf if no neighbor
        d2 = fmaxf(d2, 0.0f);
        const float md = sqrtf(d2);
        out[i] = (prev[i] + md * wmean) * 0.5f;
    }
}

extern "C" void kernel_launch(void* const* d_in, const int* in_sizes, int n_in,
                              void* d_out, int out_size, void* d_ws, size_t ws_size,
                              hipStream_t stream) {
    const float* prev    = (const float*)d_in[0];
    const float* nodes   = (const float*)d_in[1];
    const int*   adj     = (const int*)d_in[2];
    const float* W_phi   = (const float*)d_in[3];
    const float* W_theta = (const float*)d_in[4];
    float* out = (float*)d_out;

    float4* packed = (float4*)d_ws;   // 128 KB

    prep_kernel<<<(NN + TPB - 1) / TPB, TPB, 0, stream>>>(nodes, W_theta, packed);

    maxdist_kernel<<<NN / ROWS, TPB, 0, stream>>>(prev, adj, W_phi, packed, out);
}